// Round 1
// baseline (729.697 us; speedup 1.0000x reference)
//
#include <hip/hip_runtime.h>

// Trilinear sparse-voxel upsampling, SCALE=2, R=128, C=32.
// fine = 2*c + o (o in {0,1}^3)  =>  base = c-1+o, frac = 0.75-0.5*o per axis.
// Per-axis neighbors: {c-1+o (w=0.25+0.5o), c+o (w=0.75-0.5o)} -- exact fp32.

#define R 128
#define TABLE_ELEMS (R * R * R)

__global__ void build_table_kernel(const int* __restrict__ coarse,
                                   int* __restrict__ table, int n) {
    int i = blockIdx.x * blockDim.x + threadIdx.x;
    if (i >= n) return;
    int x = coarse[i * 3 + 0];
    int y = coarse[i * 3 + 1];
    int z = coarse[i * 3 + 2];
    int lin = (x * R + y) * R + z;
    // numpy last-write-wins with increasing values == max row index
    atomicMax(&table[lin], i);
}

__global__ void __launch_bounds__(256)
upsample_kernel(const float4* __restrict__ feat4,   // [n_in, 8] float4 == [n_in,32] f32
                const int* __restrict__ coarse,     // [n_in, 3]
                const int* __restrict__ table,      // [128^3]
                float4* __restrict__ out4,          // [8*n_in, 8] float4
                int n_in) {
    int gid = blockIdx.x * blockDim.x + threadIdx.x;   // n_in*64 threads
    int total = n_in * 64;
    if (gid >= total) return;

    int part = gid & 7;        // which float4 of the 32-channel row
    int m    = gid >> 3;       // fine voxel index [0, 8*n_in)
    int vi   = m >> 3;         // input (coarse) voxel
    int fo   = m & 7;          // child offset bits (x,y,z) = (fo>>2, fo>>1, fo)&1

    int cx = coarse[vi * 3 + 0];
    int cy = coarse[vi * 3 + 1];
    int cz = coarse[vi * 3 + 2];
    int ox = (fo >> 2) & 1;
    int oy = (fo >> 1) & 1;
    int oz = fo & 1;

    // lower/upper neighbor coord + weight per axis (exact)
    int   x0 = cx - 1 + ox, x1 = cx + ox;
    int   y0 = cy - 1 + oy, y1 = cy + oy;
    int   z0 = cz - 1 + oz, z1 = cz + oz;
    float wx0 = 0.25f + 0.5f * (float)ox, wx1 = 0.75f - 0.5f * (float)ox;
    float wy0 = 0.25f + 0.5f * (float)oy, wy1 = 0.75f - 0.5f * (float)oy;
    float wz0 = 0.25f + 0.5f * (float)oz, wz1 = 0.75f - 0.5f * (float)oz;

    float4 acc = make_float4(0.f, 0.f, 0.f, 0.f);

#pragma unroll
    for (int k = 0; k < 8; ++k) {
        int kx = (k >> 2) & 1;
        int ky = (k >> 1) & 1;
        int kz = k & 1;
        int x = kx ? x1 : x0;
        int y = ky ? y1 : y0;
        int z = kz ? z1 : z0;
        float w = (kx ? wx1 : wx0) * (ky ? wy1 : wy0) * (kz ? wz1 : wz0);
        if ((unsigned)x < (unsigned)R && (unsigned)y < (unsigned)R &&
            (unsigned)z < (unsigned)R) {
            int idx = table[(x * R + y) * R + z];
            if (idx >= 0) {
                float4 f = feat4[(long long)idx * 8 + part];
                acc.x += w * f.x;
                acc.y += w * f.y;
                acc.z += w * f.z;
                acc.w += w * f.w;
            }
        }
    }

    out4[(long long)m * 8 + part] = acc;
}

extern "C" void kernel_launch(void* const* d_in, const int* in_sizes, int n_in_arrs,
                              void* d_out, int out_size, void* d_ws, size_t ws_size,
                              hipStream_t stream) {
    const float* feat  = (const float*)d_in[0];
    const int* coarse  = (const int*)d_in[1];
    // d_in[2] (fine_coords) is derivable from coarse_coords -- not read.

    int n_in = in_sizes[1] / 3;            // 400000
    int* table = (int*)d_ws;               // 8 MB scratch

    // init hash table to -1 (0xFF bytes) -- capture-safe async memset
    hipMemsetAsync(table, 0xFF, (size_t)TABLE_ELEMS * sizeof(int), stream);

    build_table_kernel<<<(n_in + 255) / 256, 256, 0, stream>>>(coarse, table, n_in);

    int total = n_in * 64;                 // 8 children * 8 float4-parts
    upsample_kernel<<<(total + 255) / 256, 256, 0, stream>>>(
        (const float4*)feat, coarse, table, (float4*)d_out, n_in);
}